// Round 1
// baseline (244.280 us; speedup 1.0000x reference)
//
#include <hip/hip_runtime.h>

// IRFDeconv3D: out[b,p,t] = sum_{tau<=t} data[b,p,tau] * knorm[b,t-tau]
// == per-batch GEMM A[16384x256] @ Toeplitz(knorm)[256x256], keep n<256.
//
// v5: exploit the Toeplitz structure. The B-fragment for (k-slab kk, n-tile j)
// depends only on d = j - 2*kk, so there are only 16 distinct 32x16 B
// fragments per batch (16 KiB). Each wave loads them ONCE; the K-loop has
// zero loads. A is loaded upfront (16 dwordx4, one HBM latency per wave).
// MFMA operands are SWAPPED (mfma(bd, a, acc) computes the transposed tile)
// so each lane holds 4 consecutive time bins of one pixel row -> the
// epilogue is 16 coalesced dwordx4 stores instead of 64 scalar stores.
//
// Traffic: read 128 MiB A + write 128 MiB out => ~43 us roofline at 6.3 TB/s.

typedef __attribute__((ext_vector_type(8))) short short8;
typedef __attribute__((ext_vector_type(4))) float floatx4;

#define T_BINS 256
#define PIX_PER_B (128 * 128)

__device__ inline unsigned short f2bf(float f) {
    unsigned int u = __float_as_uint(f);
    u += 0x7fffu + ((u >> 16) & 1u);   // round-to-nearest-even
    return (unsigned short)(u >> 16);
}

// Wd[b][d][n'][kl] (bf16) = knorm[16*d + n' - kl] if idx >= 0 else 0.
// d in [0,16), n' in [0,16), kl in [0,32). 16 KiB per batch, 128 KiB total.
__global__ __launch_bounds__(256) void build_W(const float* __restrict__ irf,
                                               unsigned short* __restrict__ W) {
    __shared__ float red[256];
    __shared__ float knorm[256];
    const int b = blockIdx.x;
    const int t = threadIdx.x;
    float v = irf[b * T_BINS + t];
    red[t] = v;
    __syncthreads();
    for (int s = 128; s > 0; s >>= 1) {
        if (t < s) red[t] = fmaxf(red[t], red[t + s]);
        __syncthreads();
    }
    knorm[t] = v / red[0];
    __syncthreads();
    unsigned short* Wb = W + b * 8192;
#pragma unroll
    for (int i = 0; i < 32; i++) {
        int e = i * 256 + t;            // coalesced
        int d  = e >> 9;
        int np = (e >> 5) & 15;
        int kl = e & 31;
        int idx = 16 * d + np - kl;
        Wb[e] = (idx >= 0) ? f2bf(knorm[idx]) : (unsigned short)0;
    }
}

__device__ inline short8 cvt_a(float4 lo, float4 hi) {
    short8 a;
    a[0] = (short)f2bf(lo.x); a[1] = (short)f2bf(lo.y);
    a[2] = (short)f2bf(lo.z); a[3] = (short)f2bf(lo.w);
    a[4] = (short)f2bf(hi.x); a[5] = (short)f2bf(hi.y);
    a[6] = (short)f2bf(hi.z); a[7] = (short)f2bf(hi.w);
    return a;
}

__global__ __launch_bounds__(256, 2) void conv_gemm(const float* __restrict__ data,
                                                    const unsigned short* __restrict__ W,
                                                    float* __restrict__ out) {
    const int b = blockIdx.x >> 8;        // 256 m-tiles per batch
    const int mt = blockIdx.x & 255;
    const int t = threadIdx.x;
    const int w = t >> 6;                 // wave id (0..3); waves independent
    const int l = t & 63;
    const int lq = l >> 4;                // quad (0..3)
    const int lm = l & 15;

    const int row = mt * 64 + w * 16 + lm;            // this lane's A row
    const float* Arow = data + ((size_t)b * PIX_PER_B + row) * T_BINS;
    const unsigned short* Wd = W + b * 8192;

    // ---- B diagonals: loop-invariant, 16 loads total (L1/L2-hot) ----
    short8 bd[16];
#pragma unroll
    for (int d = 0; d < 16; d++)
        bd[d] = *(const short8*)(Wd + d * 512 + lm * 32 + lq * 8);

    // ---- entire A row slice upfront: 16 x dwordx4, one HBM latency ----
    float4 araw[8][2];
#pragma unroll
    for (int kk = 0; kk < 8; kk++) {
        araw[kk][0] = *(const float4*)(Arow + kk * 32 + lq * 8);
        araw[kk][1] = *(const float4*)(Arow + kk * 32 + lq * 8 + 4);
    }
    __builtin_amdgcn_sched_barrier(0);   // pin the load issue here (don't sink)

    floatx4 acc[16];
#pragma unroll
    for (int j = 0; j < 16; j++) acc[j] = (floatx4){0.f, 0.f, 0.f, 0.f};

    // ---- K loop: zero loads, pure cvt + MFMA; triangular skip j < 2*kk ----
#pragma unroll
    for (int kk = 0; kk < 8; kk++) {
        short8 a = cvt_a(araw[kk][0], araw[kk][1]);
#pragma unroll
        for (int j = 2 * kk; j < 16; j++) {
            // swapped operands: computes the transposed tile
            acc[j] = __builtin_amdgcn_mfma_f32_16x16x32_bf16(bd[j - 2 * kk], a,
                                                             acc[j], 0, 0, 0);
        }
    }

    // ---- epilogue: D layout (swapped) -> lane owns pixel row lm,
    //      times 16*j + 4*lq + r (r=0..3 consecutive) -> dwordx4 stores ----
    float* Orow = out + ((size_t)b * PIX_PER_B + mt * 64 + w * 16 + lm) * T_BINS;
#pragma unroll
    for (int j = 0; j < 16; j++) {
        *reinterpret_cast<floatx4*>(Orow + 16 * j + 4 * lq) = acc[j];
    }
}

extern "C" void kernel_launch(void* const* d_in, const int* in_sizes, int n_in,
                              void* d_out, int out_size, void* d_ws, size_t ws_size,
                              hipStream_t stream) {
    const float* data = (const float*)d_in[0];   // [8,128,128,256,1] fp32
    const float* irf  = (const float*)d_in[1];   // [8,1,1,256,1] fp32
    float* outp = (float*)d_out;                 // [8,128,128,256,1] fp32
    unsigned short* W = (unsigned short*)d_ws;   // 8*16*16*32 bf16 = 128 KiB

    build_W<<<8, 256, 0, stream>>>(irf, W);
    conv_gemm<<<2048, 256, 0, stream>>>(data, W, outp);
}

// Round 2
// 243.792 us; speedup vs baseline: 1.0020x; 1.0020x over previous
//
#include <hip/hip_runtime.h>

// IRFDeconv3D: out[b,p,t] = sum_{tau<=t} data[b,p,tau] * knorm[b,t-tau]
// == per-batch GEMM A[16384x256] @ Toeplitz(knorm)[256x256], keep n<256.
//
// v6: occupancy attack. v5 was latency-bound at 2 waves/SIMD because the
// unified VGPR/AGPR file held bd[16] (64) + acc[16] (64) + staging (~190
// total). Changes:
//  - B diagonals (16 KiB/batch) staged in LDS per block, ds_read_b128 per
//    use: frees 64 regs, dedups the 4x per-wave redundant global B loads.
//  - j-OUTER loop: output tile j needs only slabs kk <= j/2, so tiles
//    2kk,2kk+1 are finished+stored right after slab kk arrives. acc drops
//    from 16 live f32x4 to 2 -> frees another ~56 regs.
//  - A: 4-deep float4 prefetch pipeline (32 regs in flight), cvt to bf16
//    on arrival (af[8] = 32 regs).
//  - __launch_bounds__(256,4): 4 waves/SIMD (<=128 regs), 16 waves/CU.

typedef __attribute__((ext_vector_type(8))) short short8;
typedef __attribute__((ext_vector_type(4))) float floatx4;

#define T_BINS 256
#define PIX_PER_B (128 * 128)

__device__ inline unsigned short f2bf(float f) {
    unsigned int u = __float_as_uint(f);
    u += 0x7fffu + ((u >> 16) & 1u);   // round-to-nearest-even
    return (unsigned short)(u >> 16);
}

// Wd[b][d][n'][kl] (bf16) = knorm[16*d + n' - kl] if idx >= 0 else 0.
// d in [0,16), n' in [0,16), kl in [0,32). 16 KiB per batch, 128 KiB total.
__global__ __launch_bounds__(256) void build_W(const float* __restrict__ irf,
                                               unsigned short* __restrict__ W) {
    __shared__ float red[256];
    __shared__ float knorm[256];
    const int b = blockIdx.x;
    const int t = threadIdx.x;
    float v = irf[b * T_BINS + t];
    red[t] = v;
    __syncthreads();
    for (int s = 128; s > 0; s >>= 1) {
        if (t < s) red[t] = fmaxf(red[t], red[t + s]);
        __syncthreads();
    }
    knorm[t] = v / red[0];
    __syncthreads();
    unsigned short* Wb = W + b * 8192;
#pragma unroll
    for (int i = 0; i < 32; i++) {
        int e = i * 256 + t;            // coalesced
        int d  = e >> 9;
        int np = (e >> 5) & 15;
        int kl = e & 31;
        int idx = 16 * d + np - kl;
        Wb[e] = (idx >= 0) ? f2bf(knorm[idx]) : (unsigned short)0;
    }
}

__device__ inline short8 cvt_a(float4 lo, float4 hi) {
    short8 a;
    a[0] = (short)f2bf(lo.x); a[1] = (short)f2bf(lo.y);
    a[2] = (short)f2bf(lo.z); a[3] = (short)f2bf(lo.w);
    a[4] = (short)f2bf(hi.x); a[5] = (short)f2bf(hi.y);
    a[6] = (short)f2bf(hi.z); a[7] = (short)f2bf(hi.w);
    return a;
}

__global__ __launch_bounds__(256, 4) void conv_gemm(const float* __restrict__ data,
                                                    const unsigned short* __restrict__ W,
                                                    float* __restrict__ out) {
    const int b = blockIdx.x >> 8;        // 256 m-tiles per batch
    const int mt = blockIdx.x & 255;
    const int t = threadIdx.x;
    const int w = t >> 6;                 // wave id (0..3); waves independent
    const int l = t & 63;
    const int lq = l >> 4;                // quad (0..3)
    const int lm = l & 15;

    // ---- stage B diagonal table (16 KiB) into LDS, shared by all 4 waves ----
    __shared__ unsigned short Bs[8192];
    {
        const short8* src = (const short8*)(W + b * 8192);
        short8* dst = (short8*)Bs;
#pragma unroll
        for (int i = 0; i < 4; i++)       // 1024 short8 chunks / 256 threads
            dst[i * 256 + t] = src[i * 256 + t];   // coalesced, 16B/lane
    }

    const int row = mt * 64 + w * 16 + lm;            // this lane's A row
    const float* Arow = data + ((size_t)b * PIX_PER_B + row) * T_BINS;

    // ---- A prefetch pipeline: 4 slabs of float4 pairs in flight ----
    float4 fbuf[4][2];
#pragma unroll
    for (int kk = 0; kk < 4; kk++) {
        fbuf[kk][0] = *(const float4*)(Arow + kk * 32 + lq * 8);
        fbuf[kk][1] = *(const float4*)(Arow + kk * 32 + lq * 8 + 4);
    }

    __syncthreads();                      // Bs ready (overlapped with A issue)

    float* Orow = out + ((size_t)b * PIX_PER_B + row) * T_BINS;
    const unsigned short* BsLane = Bs + lm * 32 + lq * 8;  // +d*512 per frag

    short8 af[8];                         // bf16 A slabs, kept live (32 regs)

#pragma unroll
    for (int kk = 0; kk < 8; kk++) {
        const int cb = kk & 3;
        af[kk] = cvt_a(fbuf[cb][0], fbuf[cb][1]);
        if (kk + 4 < 8) {                 // refill freed buffer
            fbuf[cb][0] = *(const float4*)(Arow + (kk + 4) * 32 + lq * 8);
            fbuf[cb][1] = *(const float4*)(Arow + (kk + 4) * 32 + lq * 8 + 4);
        }
        // tiles j = 2kk, 2kk+1 are now complete: finish and store them
#pragma unroll
        for (int jo = 0; jo < 2; jo++) {
            const int j = 2 * kk + jo;
            floatx4 acc = (floatx4){0.f, 0.f, 0.f, 0.f};
#pragma unroll
            for (int k2 = 0; k2 <= kk; k2++) {
                const int d = j - 2 * k2;
                short8 bf = *(const short8*)(BsLane + d * 512);
                // swapped operands: computes the transposed tile
                acc = __builtin_amdgcn_mfma_f32_16x16x32_bf16(bf, af[k2],
                                                              acc, 0, 0, 0);
            }
            // lane owns pixel row lm; times 16j+4lq+r consecutive
            *reinterpret_cast<floatx4*>(Orow + 16 * j + 4 * lq) = acc;
        }
    }
}

extern "C" void kernel_launch(void* const* d_in, const int* in_sizes, int n_in,
                              void* d_out, int out_size, void* d_ws, size_t ws_size,
                              hipStream_t stream) {
    const float* data = (const float*)d_in[0];   // [8,128,128,256,1] fp32
    const float* irf  = (const float*)d_in[1];   // [8,1,1,256,1] fp32
    float* outp = (float*)d_out;                 // [8,128,128,256,1] fp32
    unsigned short* W = (unsigned short*)d_ws;   // 8*16*16*32 bf16 = 128 KiB

    build_W<<<8, 256, 0, stream>>>(irf, W);
    conv_gemm<<<2048, 256, 0, stream>>>(data, W, outp);
}